// Round 13
// baseline (334.291 us; speedup 1.0000x reference)
//
#include <hip/hip_runtime.h>
#include <hip/hip_bf16.h>

#define NPTS 256
#define NB   4
#define KNN  27
#define EPSV 1e-5f

typedef unsigned short u16;
typedef _Float16 f16;
typedef __attribute__((ext_vector_type(8))) _Float16 f16x8;
typedef __attribute__((ext_vector_type(4))) _Float16 f16x4;
typedef __attribute__((ext_vector_type(4))) float f32x4;

// ---------------- workspace layout (bytes); ws = 256 MiB ----------------
#define OFF_IDX    0           // 1024*28*4 = 114688 (idx stride padded to 28)
#define OFF_XYZ    131072      // 4*256*32*2 = 65536   f16 [b][n][32]
#define OFF_A0     262144      // 128*32*2    = 8192
#define OFF_A1     270336      // 384*96*2    = 73728
#define OFF_A2     344064      // 1536*384*2  = 1179648
#define OFF_A3     1523712     // 6144*1536*2 = 18874368
#define OFF_A4     20398080    // 256*8160*2  = 4177920
#define OFF_PQ     24576000    // partial planes
#define OFF_SLICE  74907648    // (unused since r13 fusion)
#define OFF_XC     100073472   // 4*256*8160*2 = 16711680  f16 [b][n][8160]
#define OFF_Y      116785152   // 16*4*256*256*4 = 16777216
// end ~134 MB

// ---------------- global -> LDS direct DMA (16B/lane) ----------------
typedef __attribute__((address_space(3))) unsigned int lds_u32_t;
typedef __attribute__((address_space(1))) unsigned int glb_u32_t;

__device__ __forceinline__ void gload16(const f16* g, const u16* l) {
    __builtin_amdgcn_global_load_lds((const glb_u32_t*)g, (lds_u32_t*)(u16*)l, 16, 0, 0);
}

__device__ __forceinline__ float dist3_nocontract(float ax, float ay, float az,
                                                  float bx, float by, float bz) {
#pragma clang fp contract(off)
    float dx = bx - ax, dy = by - ay, dz = bz - az;
    float s = dx * dx;
    s = s + dy * dy;
    s = s + dz * dz;
    return s;
}

// ---------------- kNN + weight prep, one dispatch ----------------
// blocks [0,256): kNN, 4 points per block (one per wave). CONTIGUOUS head
// placement: consecutive slots round-robin across all 256 CUs -> 1 kNN
// block/CU. [r11 post-mortem: modular interleave (bid&15)==15 aliased to
// 16 CUs, serializing 16 deep. Power-of-2 interleaves concentrate.]
// blocks [256, 4557): weight prep, pbid = bid - 256.
__global__ __launch_bounds__(256) void knn_prep(
    const float* __restrict__ x, int* __restrict__ idx, f16* __restrict__ xyz,
    const float* __restrict__ w0, const float* __restrict__ w1,
    const float* __restrict__ w2, const float* __restrict__ w3,
    const float* __restrict__ w4, char* __restrict__ ws)
{
    int bid = blockIdx.x;
    int tid = threadIdx.x;

    if (bid < 256) {
        // ---- kNN path: 4 points per block, one per wave ----
        int wid = tid >> 6;
        int lane = tid & 63;
        int pt = bid * 4 + wid;         // 0..1023
        int b = pt >> 8, n = pt & 255;

        float xp0 = x[pt * 3 + 0];
        float xp1 = x[pt * 3 + 1];
        float xp2 = x[pt * 3 + 2];

        if (lane < 32) {
            float v = (lane < 3) ? x[pt * 3 + lane] : 0.f;
            xyz[((long)b * NPTS + n) * 32 + lane] = (f16)v;
        }

        unsigned long long key[4];
#pragma unroll
        for (int u = 0; u < 4; ++u) {
            int j = lane + 64 * u;
            int gj = b * NPTS + j;
            float d = dist3_nocontract(xp0, xp1, xp2,
                                       x[gj * 3 + 0], x[gj * 3 + 1], x[gj * 3 + 2]);
            key[u] = ((unsigned long long)__float_as_uint(d) << 32) | (unsigned int)j;
        }

        for (int r = 0; r < KNN; ++r) {
            unsigned long long m = key[0];
            m = key[1] < m ? key[1] : m;
            m = key[2] < m ? key[2] : m;
            m = key[3] < m ? key[3] : m;
#pragma unroll
            for (int off = 32; off; off >>= 1) {
                unsigned long long o = __shfl_xor(m, off);
                m = o < m ? o : m;
            }
            if (lane == 0) idx[pt * 28 + r] = (int)(m & 0xffffffffu);
#pragma unroll
            for (int u = 0; u < 4; ++u)
                if (key[u] == m) key[u] = ~0ULL;
        }
        return;
    }

    int pbid = bid - 256;

    if (pbid == 0) {
        // ---- w0: K=3, Kpad=32, Co=48; rows 0..95 values, 96..127 zero ----
        f16* A = (f16*)(ws + OFF_A0);
        int jj = tid >> 2;              // 0..63
        int cc = (tid & 3) * 8;         // 0,8,16,24
        if (jj < 48) {
            f16x8 lo = {}, df = {};
#pragma unroll
            for (int j = 0; j < 8; ++j) {
                int c = cc + j;
                if (c < 3) {
                    float a = w0[jj * 6 + c];
                    float b2 = w0[jj * 6 + 3 + c];
                    lo[j] = (f16)a;
                    df[j] = (f16)(b2 - a);
                }
            }
            *(f16x8*)&A[jj * 32 + cc] = lo;
            *(f16x8*)&A[(48 + jj) * 32 + cc] = df;
        }
        if (jj < 32) {                  // zero rows 96..127
            f16x8 z = {};
            *(f16x8*)&A[(96 + jj) * 32 + cc] = z;
        }
        return;
    }
    if (pbid < 13) {
        // ---- w1: K=96, Co=192; 16 rows/block, 16 thr/row (12 active) ----
        f16* A = (f16*)(ws + OFF_A1);
        int j = (pbid - 1) * 16 + (tid >> 4);
        int cc = (tid & 15) * 8;
        if (cc >= 96) return;
        f32x4 a0 = *(const f32x4*)&w1[j * 192 + cc];
        f32x4 a1 = *(const f32x4*)&w1[j * 192 + cc + 4];
        f32x4 b0 = *(const f32x4*)&w1[j * 192 + 96 + cc];
        f32x4 b1 = *(const f32x4*)&w1[j * 192 + 96 + cc + 4];
        f16x8 lo, df;
#pragma unroll
        for (int j2 = 0; j2 < 4; ++j2) {
            lo[j2] = (f16)a0[j2];     lo[4 + j2] = (f16)a1[j2];
            df[j2] = (f16)(b0[j2] - a0[j2]);
            df[4 + j2] = (f16)(b1[j2] - a1[j2]);
        }
        *(f16x8*)&A[j * 96 + cc] = lo;
        *(f16x8*)&A[(192 + j) * 96 + cc] = df;
        return;
    }
    if (pbid < 205) {
        // ---- w2: K=384, Co=768; 4 rows/block, 64 thr/row (48 active) ----
        f16* A = (f16*)(ws + OFF_A2);
        int j = (pbid - 13) * 4 + (tid >> 6);
        int cc = (tid & 63) * 8;
        if (cc >= 384) return;
        f32x4 a0 = *(const f32x4*)&w2[(long)j * 768 + cc];
        f32x4 a1 = *(const f32x4*)&w2[(long)j * 768 + cc + 4];
        f32x4 b0 = *(const f32x4*)&w2[(long)j * 768 + 384 + cc];
        f32x4 b1 = *(const f32x4*)&w2[(long)j * 768 + 384 + cc + 4];
        f16x8 lo, df;
#pragma unroll
        for (int j2 = 0; j2 < 4; ++j2) {
            lo[j2] = (f16)a0[j2];     lo[4 + j2] = (f16)a1[j2];
            df[j2] = (f16)(b0[j2] - a0[j2]);
            df[4 + j2] = (f16)(b1[j2] - a1[j2]);
        }
        *(f16x8*)&A[(long)j * 384 + cc] = lo;
        *(f16x8*)&A[(long)(768 + j) * 384 + cc] = df;
        return;
    }
    if (pbid < 3277) {
        // ---- w3: K=1536, Co=3072; 1 row/block, 192 thr active ----
        f16* A = (f16*)(ws + OFF_A3);
        int j = pbid - 205;
        int cc = tid * 8;
        if (cc >= 1536) return;
        f32x4 a0 = *(const f32x4*)&w3[(long)j * 3072 + cc];
        f32x4 a1 = *(const f32x4*)&w3[(long)j * 3072 + cc + 4];
        f32x4 b0 = *(const f32x4*)&w3[(long)j * 3072 + 1536 + cc];
        f32x4 b1 = *(const f32x4*)&w3[(long)j * 3072 + 1536 + cc + 4];
        f16x8 lo, df;
#pragma unroll
        for (int j2 = 0; j2 < 4; ++j2) {
            lo[j2] = (f16)a0[j2];     lo[4 + j2] = (f16)a1[j2];
            df[j2] = (f16)(b0[j2] - a0[j2]);
            df[4 + j2] = (f16)(b1[j2] - a1[j2]);
        }
        *(f16x8*)&A[(long)j * 1536 + cc] = lo;
        *(f16x8*)&A[(long)(3072 + j) * 1536 + cc] = df;
        return;
    }
    {
        // ---- w4: 256 x 8160, straight copy to f16 ----
        f16* A = (f16*)(ws + OFF_A4);
        int loc = pbid - 3277;
        int r = loc >> 2;
        int c0 = (loc & 3) * 2048 + tid * 8;
        if (c0 >= 8160) return;
        f32x4 a0 = *(const f32x4*)&w4[(long)r * 8160 + c0];
        f32x4 a1 = *(const f32x4*)&w4[(long)r * 8160 + c0 + 4];
        f16x8 hv;
#pragma unroll
        for (int j2 = 0; j2 < 4; ++j2) {
            hv[j2] = (f16)a0[j2];
            hv[4 + j2] = (f16)a1[j2];
        }
        *(f16x8*)&A[(long)r * 8160 + c0] = hv;
        return;
    }
}

// ---------------- f16 MFMA GEMM, split-K, depth-4 counted-vmcnt pipeline ----
// [FROZEN — r7 config, measured optimum across 5 variants (r2/r6/r7/r8/r9).
//  BN=64 regresses (LDS-read ratio); BK=64 depth-2 regresses (loses counted
//  depth). Do not re-try those.]
__global__ __launch_bounds__(256) void gemm_mfma(
    const f16* __restrict__ A, const f16* __restrict__ B,
    float* __restrict__ out, int M, int Kpad, int K,
    int ldF, long bsF, long bsO, int nsplit, long pstride)
{
    __shared__ u16 sS[4][2][4096];     // [buf][A/B][128*32]

    int bz = blockIdx.z;
    int b = bz / nsplit, slice = bz - b * nsplit;
    int kchunk = (((K + nsplit - 1) / nsplit) + 31) & ~31;
    int kstart = slice * kchunk;
    int kend = K < kstart + kchunk ? K : kstart + kchunk;
    int nt = (kend - kstart) >> 5;          // K multiple of 32 always

    const f16* pB = B + (long)b * bsF;
    float* Ob = out + (long)slice * pstride + (long)b * bsO;

    int m0 = blockIdx.x * 128, n0 = blockIdx.y * 128;
    int tid = threadIdx.x, lane = tid & 63, wid = tid >> 6;
    int wm = (wid >> 1) * 64, wn = (wid & 1) * 64;
    int lrow = lane & 15, quad = lane >> 4;

    int r0 = wid * 16 + (lane >> 2);
    int r1 = 64 + r0;
    int ck = lane & 3;
    int c0 = (ck ^ ((r0 >> 1) & 3)) * 8;
    int c1 = (ck ^ ((r1 >> 1) & 3)) * 8;

    const f16* gA0 = A + (long)(m0 + r0) * Kpad + c0 + kstart;
    const f16* gA1 = A + (long)(m0 + r1) * Kpad + c1 + kstart;
    const f16* gB0 = pB + (long)(n0 + r0) * ldF + c0 + kstart;
    const f16* gB1 = pB + (long)(n0 + r1) * ldF + c1 + kstart;

    int oA0 = (wid * 16) * 32;              // wave-uniform LDS element offsets
    int oA1 = (64 + wid * 16) * 32;

    int fs = (quad ^ ((lrow >> 1) & 3)) * 8;
    int offA = (wm + lrow) * 32 + fs;
    int offB = (wn + lrow) * 32 + fs;

    f32x4 acc[4][4] = {};

#define STAGE(bf)                                                  \
    do {                                                           \
        gload16(gA0, &sS[bf][0][oA0]);                             \
        gload16(gA1, &sS[bf][0][oA1]);                             \
        gload16(gB0, &sS[bf][1][oA0]);                             \
        gload16(gB1, &sS[bf][1][oA1]);                             \
        gA0 += 32; gA1 += 32; gB0 += 32; gB1 += 32;                \
    } while (0)

    // prologue: stage up to 3 tiles (oldest first)
    STAGE(0);
    if (nt > 1) STAGE(1);
    if (nt > 2) STAGE(2);

    for (int t = 0; t < nt; ++t) {
        int rem = nt - 1 - t;
        if (rem >= 2)      asm volatile("s_waitcnt vmcnt(8)" ::: "memory");
        else if (rem == 1) asm volatile("s_waitcnt vmcnt(4)" ::: "memory");
        else               asm volatile("s_waitcnt vmcnt(0)" ::: "memory");
        __builtin_amdgcn_s_barrier();

        if (t + 3 < nt) STAGE((t + 3) & 3);

        const u16* bA = &sS[t & 3][0][0];
        const u16* bB = &sS[t & 3][1][0];
        f16x8 fb[4];
#pragma unroll
        for (int nt4 = 0; nt4 < 4; ++nt4)
            fb[nt4] = *(const f16x8*)&bB[offB + nt4 * 512];
        __builtin_amdgcn_s_setprio(1);
#pragma unroll
        for (int mt = 0; mt < 4; ++mt) {
            f16x8 fa = *(const f16x8*)&bA[offA + mt * 512];
#pragma unroll
            for (int nt4 = 0; nt4 < 4; ++nt4)
                acc[mt][nt4] = __builtin_amdgcn_mfma_f32_16x16x32_f16(fa, fb[nt4], acc[mt][nt4], 0, 0, 0);
        }
        __builtin_amdgcn_s_setprio(0);
    }
#undef STAGE

    // epilogue: C/D layout col=lane&15, row=quad*4+reg  [m89-verified]
#pragma unroll
    for (int mt = 0; mt < 4; ++mt)
#pragma unroll
        for (int nt4 = 0; nt4 < 4; ++nt4) {
            int C = n0 + wn + nt4 * 16 + lrow;
            int Rb = m0 + wm + mt * 16 + quad * 4;
#pragma unroll
            for (int r = 0; r < 4; ++r) {
                int R = Rb + r;
                if (R < M) Ob[(long)R * NPTS + C] = acc[mt][nt4][r];
            }
        }
}

// ---------------- fused gather + stats + BN/lrelu + tp + TRANSPOSED write --
// Replaces gather_finalize + transpose_cn (r13 fusion). Block handles NO=4
// consecutive o's SEQUENTIALLY (p_sh reused per-o -> VGPR stays ~r12 level;
// avoids the r4 register blowup). val accumulated f32 in LDS, then written
// directly to xc [b][n][8160] as f16x4 (val at offc+o0, tp at offc+Co+o0).
// Arithmetic, order, and f16 rounding points identical to the split version.
// Saves: slice round-trip (2x12.6 MB/layer), 4 transpose dispatches, and
// 3/4 of the idx L2 traffic (L1-hit on oo>0 reloads).
template <int NO>
__global__ __launch_bounds__(512) void gather_tx(
    const float* __restrict__ PQ, long pstride, int nsplit,
    const int* __restrict__ idx,
    const float* __restrict__ g, const float* __restrict__ beta,
    f16* __restrict__ xc, int Co, int offc)
{
    __shared__ float p_sh[NB][NPTS];
    __shared__ float val_sh[NO][NB][NPTS];
    __shared__ float red[2][NB][2];
    int o0 = blockIdx.x * NO;
    int tid = threadIdx.x;
    int b = tid >> 7;           // 0..3
    int l128 = tid & 127;       // 0..127
    int wh = (tid >> 6) & 1;    // wave-half within b-group

#define G3(cu)                                                      \
    { float p;                                                      \
      p = p_sh[b][cu.x]; sp += p; spp = fmaf(p, p, spp);            \
      pmx = fmaxf(pmx, p); pmn = fminf(pmn, p);                     \
      p = p_sh[b][cu.y]; sp += p; spp = fmaf(p, p, spp);            \
      pmx = fmaxf(pmx, p); pmn = fminf(pmn, p);                     \
      p = p_sh[b][cu.z]; sp += p; spp = fmaf(p, p, spp);            \
      pmx = fmaxf(pmx, p); pmn = fminf(pmn, p); }
#define G4(cu)                                                      \
    { G3(cu);                                                       \
      float p = p_sh[b][cu.w]; sp += p; spp = fmaf(p, p, spp);      \
      pmx = fmaxf(pmx, p); pmn = fminf(pmn, p); }

    for (int oo = 0; oo < NO; ++oo) {
        int o = o0 + oo;
        long ip0 = ((long)b * 2 * Co + o) * NPTS;
        long iq0 = ((long)b * 2 * Co + Co + o) * NPTS;

        float qv[2];
#pragma unroll
        for (int u = 0; u < 2; ++u) {
            int n = l128 + 128 * u;
            float v = 0.f, q = 0.f;
            for (int sp2 = 0; sp2 < nsplit; ++sp2) {
                v += PQ[sp2 * pstride + ip0 + n];
                q += PQ[sp2 * pstride + iq0 + n];
            }
            p_sh[b][n] = v;     // safe: prior-oo's gathers done before its barrier B
            qv[u] = q;
        }
        __syncthreads();        // barrier A: p_sh ready

        float mx[2], mn[2];
        float s = 0.f, ss = 0.f;
#pragma unroll
        for (int u = 0; u < 2; ++u) {
            int n = l128 + 128 * u;
            const int4* ip4 = (const int4*)(idx + ((long)b * NPTS + n) * 28);

            float sp = 0.f, spp = 0.f;
            float pmx = -__builtin_inff(), pmn = __builtin_inff();

            int4 t0 = ip4[0];
            int4 t1 = ip4[1];
            G4(t0); t0 = ip4[2];        // k 0..3
            G4(t1); t1 = ip4[3];        // k 4..7
            G4(t0); t0 = ip4[4];        // k 8..11
            G4(t1); t1 = ip4[5];        // k 12..15
            G4(t0); t0 = ip4[6];        // k 16..19
            G4(t1);                     // k 20..23
            G3(t0);                     // k 24..26 (slot 27 = pad, unused)

            float q = qv[u];
            s += sp + 27.f * q;
            ss += spp + q * fmaf(2.f, sp, 27.f * q);
            mx[u] = pmx + q;
            mn[u] = pmn + q;
        }

#pragma unroll
        for (int off = 32; off; off >>= 1) {
            s += __shfl_xor(s, off);
            ss += __shfl_xor(ss, off);
        }
        if ((tid & 63) == 0) { red[0][b][wh] = s; red[1][b][wh] = ss; }
        __syncthreads();        // barrier B: red ready; p_sh gathers done

        float ts = ((red[0][0][0] + red[0][0][1]) + (red[0][1][0] + red[0][1][1]))
                 + ((red[0][2][0] + red[0][2][1]) + (red[0][3][0] + red[0][3][1]));
        float tss = ((red[1][0][0] + red[1][0][1]) + (red[1][1][0] + red[1][1][1]))
                  + ((red[1][2][0] + red[1][2][1]) + (red[1][3][0] + red[1][3][1]));
        const float cnt = (float)(NB * NPTS * KNN);
        float mean = ts / cnt;
        float var = tss / cnt - mean * mean;
        float sc = g[o] * (1.0f / sqrtf(var + EPSV));
        float tt = beta[o] - mean * sc;

#pragma unroll
        for (int u = 0; u < 2; ++u) {
            int n = l128 + 128 * u;
            float v = (sc >= 0.f) ? mx[u] : mn[u];
            float z = sc * v + tt;
            val_sh[oo][b][n] = z >= 0.f ? z : 0.2f * z;
        }
    }
#undef G4
#undef G3

    __syncthreads();            // val_sh complete

    // transposed write: val rows then tp rows (each thread 2 of each)
#pragma unroll
    for (int u = 0; u < 2; ++u) {
        int row = u * 512 + tid;            // 0..1023
        int wb = row >> 8, n = row & 255;
        f16x4 hv;
#pragma unroll
        for (int oo = 0; oo < NO; ++oo)
            hv[oo] = (f16)val_sh[oo][wb][n];
        *(f16x4*)&xc[((long)wb * NPTS + n) * 8160 + offc + o0] = hv;
    }
#pragma unroll
    for (int u = 0; u < 2; ++u) {
        int row = u * 512 + tid;            // 0..1023 (wb = broadcast copy)
        int wb = row >> 8, n = row & 255;
        f16x4 hv;
#pragma unroll
        for (int oo = 0; oo < NO; ++oo)
            hv[oo] = (f16)(0.5f * (val_sh[oo][0][n] + val_sh[oo][1][n]));
        *(f16x4*)&xc[((long)wb * NPTS + n) * 8160 + offc + Co + o0] = hv;
    }
}

// ---------------- final BN + lrelu -> fp32 out (sums 16 partial y planes) ---
__global__ __launch_bounds__(256) void final_bn(const float* __restrict__ y,
                                                const float* __restrict__ g4,
                                                const float* __restrict__ b4,
                                                float* __restrict__ out) {
    __shared__ float red[8];
    int o = blockIdx.x;
    int tid = threadIdx.x;
    int lane = tid & 63, w = tid >> 6;

    float v[4];
    float s = 0.f, ss = 0.f;
#pragma unroll
    for (int b = 0; b < 4; ++b) {
        float acc = 0.f;
#pragma unroll
        for (int sp = 0; sp < 16; ++sp)
            acc += y[sp * 262144 + b * 65536 + o * 256 + tid];
        v[b] = acc;
        s += acc;
        ss += acc * acc;
    }
#pragma unroll
    for (int off = 32; off; off >>= 1) {
        s += __shfl_xor(s, off);
        ss += __shfl_xor(ss, off);
    }
    if (lane == 0) { red[w] = s; red[4 + w] = ss; }
    __syncthreads();
    s = (red[0] + red[1]) + (red[2] + red[3]);
    ss = (red[4] + red[5]) + (red[6] + red[7]);
    float mean = s / 1024.f;
    float var = ss / 1024.f - mean * mean;
    float sc = g4[o] * (1.0f / sqrtf(var + EPSV));
    float tt = b4[o] - mean * sc;
#pragma unroll
    for (int b = 0; b < 4; ++b) {
        float z = sc * v[b] + tt;
        z = z >= 0.f ? z : 0.2f * z;
        out[(long)b * 65536 + o * 256 + tid] = z;
    }
}

// ---------------- launch ----------------
extern "C" void kernel_launch(void* const* d_in, const int* in_sizes, int n_in,
                              void* d_out, int out_size, void* d_ws, size_t ws_size,
                              hipStream_t stream) {
    const float* x = (const float*)d_in[0];
    const float* wl[4];
    const float* gl[4];
    const float* bl[4];
    for (int i = 0; i < 4; ++i) {
        wl[i] = (const float*)d_in[1 + 3 * i];
        gl[i] = (const float*)d_in[2 + 3 * i];
        bl[i] = (const float*)d_in[3 + 3 * i];
    }
    const float* w4 = (const float*)d_in[13];
    const float* g4 = (const float*)d_in[14];
    const float* b4 = (const float*)d_in[15];

    char* ws = (char*)d_ws;
    int* idx = (int*)(ws + OFF_IDX);
    f16* xyz = (f16*)(ws + OFF_XYZ);
    float* PQ = (float*)(ws + OFF_PQ);
    f16* xc = (f16*)(ws + OFF_XC);
    float* y = (float*)(ws + OFF_Y);

    // kNN (blocks 0..255, contiguous head) + weight prep (blocks 256..4556)
    knn_prep<<<dim3(4557), dim3(256), 0, stream>>>(x, idx, xyz,
                                                   wl[0], wl[1], wl[2], wl[3], w4, ws);

    const int Kp[4] = {32, 96, 384, 1536};     // padded K (multiples of 32)
    const int Co[4] = {48, 192, 768, 3072};
    const int offc[4] = {0, 96, 480, 2016};
    const int inoff[4] = {0, 0, 96, 480};
    const int nsp[4] = {1, 3, 2, 1};
    const long aoff[4] = {OFF_A0, OFF_A1, OFF_A2, OFF_A3};

    for (int i = 0; i < 4; ++i) {
        int M = 2 * Co[i];
        int Mpad = (M + 127) & ~127;
        const f16* A = (const f16*)(ws + aoff[i]);

        const f16* Bp;
        int ldF;
        long bsF;
        if (i == 0) { Bp = xyz; ldF = 32; bsF = (long)NPTS * 32; }
        else { Bp = xc + inoff[i]; ldF = 8160; bsF = (long)NPTS * 8160; }

        long pstride = (long)NB * M * NPTS;   // one partial plane
        gemm_mfma<<<dim3(Mpad / 128, NPTS / 128, NB * nsp[i]), dim3(256), 0, stream>>>(
            A, Bp, PQ, M, Kp[i], Kp[i], ldF, bsF, (long)M * NPTS, nsp[i], pstride);

        gather_tx<4><<<dim3(Co[i] / 4), dim3(512), 0, stream>>>(
            PQ, pstride, nsp[i], idx, gl[i], bl[i], xc, Co[i], offc[i]);
    }

    // final projection: split-K=16 into 16 private y planes, summed in final_bn
    gemm_mfma<<<dim3(2, NPTS / 128, NB * 16), dim3(256), 0, stream>>>(
        (const f16*)(ws + OFF_A4), xc, y, 256, 8160, 8160, 8160,
        (long)NPTS * 8160, (long)256 * NPTS, 16, (long)NB * 256 * NPTS);
    final_bn<<<dim3(256), dim3(256), 0, stream>>>(y, g4, b4, (float*)d_out);
}

// Round 14
// 260.409 us; speedup vs baseline: 1.2837x; 1.2837x over previous
//
#include <hip/hip_runtime.h>
#include <hip/hip_bf16.h>

#define NPTS 256
#define NB   4
#define KNN  27
#define EPSV 1e-5f

typedef unsigned short u16;
typedef _Float16 f16;
typedef __attribute__((ext_vector_type(8))) _Float16 f16x8;
typedef __attribute__((ext_vector_type(4))) _Float16 f16x4;
typedef __attribute__((ext_vector_type(4))) float f32x4;

// ---------------- workspace layout (bytes); ws = 256 MiB ----------------
#define OFF_IDX    0           // 1024*28*4 = 114688 (idx stride padded to 28)
#define OFF_XYZ    131072      // 4*256*32*2 = 65536   f16 [b][n][32]
#define OFF_A0     262144      // 128*32*2    = 8192
#define OFF_A1     270336      // 384*96*2    = 73728
#define OFF_A2     344064      // 1536*384*2  = 1179648
#define OFF_A3     1523712     // 6144*1536*2 = 18874368
#define OFF_A4     20398080    // 256*8160*2  = 4177920
#define OFF_PQ     24576000    // partial planes
#define OFF_SLICE  74907648    // f16: 4*6144*256*2 = 12582912
#define OFF_XC     100073472   // 4*256*8160*2 = 16711680  f16 [b][n][8160]
#define OFF_Y      116785152   // 32*4*256*256*4 = 33554432
// end ~150 MB

// ---------------- global -> LDS direct DMA (16B/lane) ----------------
typedef __attribute__((address_space(3))) unsigned int lds_u32_t;
typedef __attribute__((address_space(1))) unsigned int glb_u32_t;

__device__ __forceinline__ void gload16(const f16* g, const u16* l) {
    __builtin_amdgcn_global_load_lds((const glb_u32_t*)g, (lds_u32_t*)(u16*)l, 16, 0, 0);
}

__device__ __forceinline__ float dist3_nocontract(float ax, float ay, float az,
                                                  float bx, float by, float bz) {
#pragma clang fp contract(off)
    float dx = bx - ax, dy = by - ay, dz = bz - az;
    float s = dx * dx;
    s = s + dy * dy;
    s = s + dz * dz;
    return s;
}

// ---------------- kNN + weight prep, one dispatch ----------------
// blocks [0,256): kNN, 4 points per block (one per wave), contiguous head
// (r11 lesson: power-of-2 interleaves alias onto few CUs).
// blocks [256, 4557): weight prep, pbid = bid - 256.
__global__ __launch_bounds__(256) void knn_prep(
    const float* __restrict__ x, int* __restrict__ idx, f16* __restrict__ xyz,
    const float* __restrict__ w0, const float* __restrict__ w1,
    const float* __restrict__ w2, const float* __restrict__ w3,
    const float* __restrict__ w4, char* __restrict__ ws)
{
    int bid = blockIdx.x;
    int tid = threadIdx.x;

    if (bid < 256) {
        int wid = tid >> 6;
        int lane = tid & 63;
        int pt = bid * 4 + wid;         // 0..1023
        int b = pt >> 8, n = pt & 255;

        float xp0 = x[pt * 3 + 0];
        float xp1 = x[pt * 3 + 1];
        float xp2 = x[pt * 3 + 2];

        if (lane < 32) {
            float v = (lane < 3) ? x[pt * 3 + lane] : 0.f;
            xyz[((long)b * NPTS + n) * 32 + lane] = (f16)v;
        }

        unsigned long long key[4];
#pragma unroll
        for (int u = 0; u < 4; ++u) {
            int j = lane + 64 * u;
            int gj = b * NPTS + j;
            float d = dist3_nocontract(xp0, xp1, xp2,
                                       x[gj * 3 + 0], x[gj * 3 + 1], x[gj * 3 + 2]);
            key[u] = ((unsigned long long)__float_as_uint(d) << 32) | (unsigned int)j;
        }

        for (int r = 0; r < KNN; ++r) {
            unsigned long long m = key[0];
            m = key[1] < m ? key[1] : m;
            m = key[2] < m ? key[2] : m;
            m = key[3] < m ? key[3] : m;
#pragma unroll
            for (int off = 32; off; off >>= 1) {
                unsigned long long o = __shfl_xor(m, off);
                m = o < m ? o : m;
            }
            if (lane == 0) idx[pt * 28 + r] = (int)(m & 0xffffffffu);
#pragma unroll
            for (int u = 0; u < 4; ++u)
                if (key[u] == m) key[u] = ~0ULL;
        }
        return;
    }

    int pbid = bid - 256;

    if (pbid == 0) {
        // ---- w0: K=3, Kpad=32, Co=48; rows 0..95 values, 96..127 zero ----
        f16* A = (f16*)(ws + OFF_A0);
        int jj = tid >> 2;              // 0..63
        int cc = (tid & 3) * 8;         // 0,8,16,24
        if (jj < 48) {
            f16x8 lo = {}, df = {};
#pragma unroll
            for (int j = 0; j < 8; ++j) {
                int c = cc + j;
                if (c < 3) {
                    float a = w0[jj * 6 + c];
                    float b2 = w0[jj * 6 + 3 + c];
                    lo[j] = (f16)a;
                    df[j] = (f16)(b2 - a);
                }
            }
            *(f16x8*)&A[jj * 32 + cc] = lo;
            *(f16x8*)&A[(48 + jj) * 32 + cc] = df;
        }
        if (jj < 32) {                  // zero rows 96..127
            f16x8 z = {};
            *(f16x8*)&A[(96 + jj) * 32 + cc] = z;
        }
        return;
    }
    if (pbid < 13) {
        // ---- w1: K=96, Co=192; 16 rows/block, 16 thr/row (12 active) ----
        f16* A = (f16*)(ws + OFF_A1);
        int j = (pbid - 1) * 16 + (tid >> 4);
        int cc = (tid & 15) * 8;
        if (cc >= 96) return;
        f32x4 a0 = *(const f32x4*)&w1[j * 192 + cc];
        f32x4 a1 = *(const f32x4*)&w1[j * 192 + cc + 4];
        f32x4 b0 = *(const f32x4*)&w1[j * 192 + 96 + cc];
        f32x4 b1 = *(const f32x4*)&w1[j * 192 + 96 + cc + 4];
        f16x8 lo, df;
#pragma unroll
        for (int j2 = 0; j2 < 4; ++j2) {
            lo[j2] = (f16)a0[j2];     lo[4 + j2] = (f16)a1[j2];
            df[j2] = (f16)(b0[j2] - a0[j2]);
            df[4 + j2] = (f16)(b1[j2] - a1[j2]);
        }
        *(f16x8*)&A[j * 96 + cc] = lo;
        *(f16x8*)&A[(192 + j) * 96 + cc] = df;
        return;
    }
    if (pbid < 205) {
        // ---- w2: K=384, Co=768; 4 rows/block, 64 thr/row (48 active) ----
        f16* A = (f16*)(ws + OFF_A2);
        int j = (pbid - 13) * 4 + (tid >> 6);
        int cc = (tid & 63) * 8;
        if (cc >= 384) return;
        f32x4 a0 = *(const f32x4*)&w2[(long)j * 768 + cc];
        f32x4 a1 = *(const f32x4*)&w2[(long)j * 768 + cc + 4];
        f32x4 b0 = *(const f32x4*)&w2[(long)j * 768 + 384 + cc];
        f32x4 b1 = *(const f32x4*)&w2[(long)j * 768 + 384 + cc + 4];
        f16x8 lo, df;
#pragma unroll
        for (int j2 = 0; j2 < 4; ++j2) {
            lo[j2] = (f16)a0[j2];     lo[4 + j2] = (f16)a1[j2];
            df[j2] = (f16)(b0[j2] - a0[j2]);
            df[4 + j2] = (f16)(b1[j2] - a1[j2]);
        }
        *(f16x8*)&A[(long)j * 384 + cc] = lo;
        *(f16x8*)&A[(long)(768 + j) * 384 + cc] = df;
        return;
    }
    if (pbid < 3277) {
        // ---- w3: K=1536, Co=3072; 1 row/block, 192 thr active ----
        f16* A = (f16*)(ws + OFF_A3);
        int j = pbid - 205;
        int cc = tid * 8;
        if (cc >= 1536) return;
        f32x4 a0 = *(const f32x4*)&w3[(long)j * 3072 + cc];
        f32x4 a1 = *(const f32x4*)&w3[(long)j * 3072 + cc + 4];
        f32x4 b0 = *(const f32x4*)&w3[(long)j * 3072 + 1536 + cc];
        f32x4 b1 = *(const f32x4*)&w3[(long)j * 3072 + 1536 + cc + 4];
        f16x8 lo, df;
#pragma unroll
        for (int j2 = 0; j2 < 4; ++j2) {
            lo[j2] = (f16)a0[j2];     lo[4 + j2] = (f16)a1[j2];
            df[j2] = (f16)(b0[j2] - a0[j2]);
            df[4 + j2] = (f16)(b1[j2] - a1[j2]);
        }
        *(f16x8*)&A[(long)j * 1536 + cc] = lo;
        *(f16x8*)&A[(long)(3072 + j) * 1536 + cc] = df;
        return;
    }
    {
        // ---- w4: 256 x 8160, straight copy to f16 ----
        f16* A = (f16*)(ws + OFF_A4);
        int loc = pbid - 3277;
        int r = loc >> 2;
        int c0 = (loc & 3) * 2048 + tid * 8;
        if (c0 >= 8160) return;
        f32x4 a0 = *(const f32x4*)&w4[(long)r * 8160 + c0];
        f32x4 a1 = *(const f32x4*)&w4[(long)r * 8160 + c0 + 4];
        f16x8 hv;
#pragma unroll
        for (int j2 = 0; j2 < 4; ++j2) {
            hv[j2] = (f16)a0[j2];
            hv[4 + j2] = (f16)a1[j2];
        }
        *(f16x8*)&A[(long)r * 8160 + c0] = hv;
        return;
    }
}

// ---------------- f16 MFMA GEMM, split-K, depth-4 counted-vmcnt pipeline ----
// [FROZEN — r7 config, measured optimum across 5 variants (r2/r6/r7/r8/r9).]
__global__ __launch_bounds__(256) void gemm_mfma(
    const f16* __restrict__ A, const f16* __restrict__ B,
    float* __restrict__ out, int M, int Kpad, int K,
    int ldF, long bsF, long bsO, int nsplit, long pstride)
{
    __shared__ u16 sS[4][2][4096];     // [buf][A/B][128*32]

    int bz = blockIdx.z;
    int b = bz / nsplit, slice = bz - b * nsplit;
    int kchunk = (((K + nsplit - 1) / nsplit) + 31) & ~31;
    int kstart = slice * kchunk;
    int kend = K < kstart + kchunk ? K : kstart + kchunk;
    int nt = (kend - kstart) >> 5;          // K multiple of 32 always

    const f16* pB = B + (long)b * bsF;
    float* Ob = out + (long)slice * pstride + (long)b * bsO;

    int m0 = blockIdx.x * 128, n0 = blockIdx.y * 128;
    int tid = threadIdx.x, lane = tid & 63, wid = tid >> 6;
    int wm = (wid >> 1) * 64, wn = (wid & 1) * 64;
    int lrow = lane & 15, quad = lane >> 4;

    int r0 = wid * 16 + (lane >> 2);
    int r1 = 64 + r0;
    int ck = lane & 3;
    int c0 = (ck ^ ((r0 >> 1) & 3)) * 8;
    int c1 = (ck ^ ((r1 >> 1) & 3)) * 8;

    const f16* gA0 = A + (long)(m0 + r0) * Kpad + c0 + kstart;
    const f16* gA1 = A + (long)(m0 + r1) * Kpad + c1 + kstart;
    const f16* gB0 = pB + (long)(n0 + r0) * ldF + c0 + kstart;
    const f16* gB1 = pB + (long)(n0 + r1) * ldF + c1 + kstart;

    int oA0 = (wid * 16) * 32;              // wave-uniform LDS element offsets
    int oA1 = (64 + wid * 16) * 32;

    int fs = (quad ^ ((lrow >> 1) & 3)) * 8;
    int offA = (wm + lrow) * 32 + fs;
    int offB = (wn + lrow) * 32 + fs;

    f32x4 acc[4][4] = {};

#define STAGE(bf)                                                  \
    do {                                                           \
        gload16(gA0, &sS[bf][0][oA0]);                             \
        gload16(gA1, &sS[bf][0][oA1]);                             \
        gload16(gB0, &sS[bf][1][oA0]);                             \
        gload16(gB1, &sS[bf][1][oA1]);                             \
        gA0 += 32; gA1 += 32; gB0 += 32; gB1 += 32;                \
    } while (0)

    // prologue: stage up to 3 tiles (oldest first)
    STAGE(0);
    if (nt > 1) STAGE(1);
    if (nt > 2) STAGE(2);

    for (int t = 0; t < nt; ++t) {
        int rem = nt - 1 - t;
        if (rem >= 2)      asm volatile("s_waitcnt vmcnt(8)" ::: "memory");
        else if (rem == 1) asm volatile("s_waitcnt vmcnt(4)" ::: "memory");
        else               asm volatile("s_waitcnt vmcnt(0)" ::: "memory");
        __builtin_amdgcn_s_barrier();

        if (t + 3 < nt) STAGE((t + 3) & 3);

        const u16* bA = &sS[t & 3][0][0];
        const u16* bB = &sS[t & 3][1][0];
        f16x8 fb[4];
#pragma unroll
        for (int nt4 = 0; nt4 < 4; ++nt4)
            fb[nt4] = *(const f16x8*)&bB[offB + nt4 * 512];
        __builtin_amdgcn_s_setprio(1);
#pragma unroll
        for (int mt = 0; mt < 4; ++mt) {
            f16x8 fa = *(const f16x8*)&bA[offA + mt * 512];
#pragma unroll
            for (int nt4 = 0; nt4 < 4; ++nt4)
                acc[mt][nt4] = __builtin_amdgcn_mfma_f32_16x16x32_f16(fa, fb[nt4], acc[mt][nt4], 0, 0, 0);
        }
        __builtin_amdgcn_s_setprio(0);
    }
#undef STAGE

    // epilogue: C/D layout col=lane&15, row=quad*4+reg  [m89-verified]
#pragma unroll
    for (int mt = 0; mt < 4; ++mt)
#pragma unroll
        for (int nt4 = 0; nt4 < 4; ++nt4) {
            int C = n0 + wn + nt4 * 16 + lrow;
            int Rb = m0 + wm + mt * 16 + quad * 4;
#pragma unroll
            for (int r = 0; r < 4; ++r) {
                int R = Rb + r;
                if (R < M) Ob[(long)R * NPTS + C] = acc[mt][nt4][r];
            }
        }
}

// ---------------- fused gather + stats + BN/lrelu + tp concat ---------------
// 1024 threads: b = tid>>8, ONE n per thread (27-gather serial chain, half
// of r12's 54). 2-deep pipelined int4 idx consumption (scalar mx/mn/qv ->
// lower VGPR than r12's [2]-arrays). Coalesced slice writes.
// [r13 post-mortem: fused transposed write = scatter-stores, WRITE_SIZE
//  4.3x -> keep split transpose_cn; its LDS tile earns its cost.]
__global__ __launch_bounds__(1024) void gather_finalize(
    const float* __restrict__ PQ, long pstride, int nsplit,
    const int* __restrict__ idx,
    const float* __restrict__ g, const float* __restrict__ beta,
    f16* __restrict__ slice, int Co)
{
    __shared__ float p_sh[NB][NPTS];
    __shared__ float val_sh[NB][NPTS];
    __shared__ float red[2][NB][4];
    int o = blockIdx.x;
    int tid = threadIdx.x;
    int b = tid >> 8;           // 0..3
    int n = tid & 255;          // 0..255
    int wh = (tid >> 6) & 3;    // wave index within b-group

    long ip0 = ((long)b * 2 * Co + o) * NPTS;
    long iq0 = ((long)b * 2 * Co + Co + o) * NPTS;

    float v = 0.f, q = 0.f;
    for (int sp2 = 0; sp2 < nsplit; ++sp2) {
        v += PQ[sp2 * pstride + ip0 + n];
        q += PQ[sp2 * pstride + iq0 + n];
    }
    p_sh[b][n] = v;
    __syncthreads();

#define G3(cu)                                                      \
    { float p;                                                      \
      p = p_sh[b][cu.x]; sp += p; spp = fmaf(p, p, spp);            \
      pmx = fmaxf(pmx, p); pmn = fminf(pmn, p);                     \
      p = p_sh[b][cu.y]; sp += p; spp = fmaf(p, p, spp);            \
      pmx = fmaxf(pmx, p); pmn = fminf(pmn, p);                     \
      p = p_sh[b][cu.z]; sp += p; spp = fmaf(p, p, spp);            \
      pmx = fmaxf(pmx, p); pmn = fminf(pmn, p); }
#define G4(cu)                                                      \
    { G3(cu);                                                       \
      float p = p_sh[b][cu.w]; sp += p; spp = fmaf(p, p, spp);      \
      pmx = fmaxf(pmx, p); pmn = fminf(pmn, p); }

    const int4* ip4 = (const int4*)(idx + ((long)b * NPTS + n) * 28);
    float sp = 0.f, spp = 0.f;
    float pmx = -__builtin_inff(), pmn = __builtin_inff();

    int4 t0 = ip4[0];
    int4 t1 = ip4[1];
    G4(t0); t0 = ip4[2];        // k 0..3
    G4(t1); t1 = ip4[3];        // k 4..7
    G4(t0); t0 = ip4[4];        // k 8..11
    G4(t1); t1 = ip4[5];        // k 12..15
    G4(t0); t0 = ip4[6];        // k 16..19
    G4(t1);                     // k 20..23
    G3(t0);                     // k 24..26 (slot 27 = pad, unused)
#undef G4
#undef G3

    float s = sp + 27.f * q;
    float ss = spp + q * fmaf(2.f, sp, 27.f * q);
    float mx = pmx + q;
    float mn = pmn + q;

#pragma unroll
    for (int off = 32; off; off >>= 1) {
        s += __shfl_xor(s, off);
        ss += __shfl_xor(ss, off);
    }
    if ((tid & 63) == 0) { red[0][b][wh] = s; red[1][b][wh] = ss; }
    __syncthreads();

    float ts = (((red[0][0][0] + red[0][0][1]) + (red[0][0][2] + red[0][0][3]))
             +  ((red[0][1][0] + red[0][1][1]) + (red[0][1][2] + red[0][1][3])))
             + (((red[0][2][0] + red[0][2][1]) + (red[0][2][2] + red[0][2][3]))
             +  ((red[0][3][0] + red[0][3][1]) + (red[0][3][2] + red[0][3][3])));
    float tss = (((red[1][0][0] + red[1][0][1]) + (red[1][0][2] + red[1][0][3]))
              +  ((red[1][1][0] + red[1][1][1]) + (red[1][1][2] + red[1][1][3])))
              + (((red[1][2][0] + red[1][2][1]) + (red[1][2][2] + red[1][2][3]))
              +  ((red[1][3][0] + red[1][3][1]) + (red[1][3][2] + red[1][3][3])));
    const float cnt = (float)(NB * NPTS * KNN);
    float mean = ts / cnt;
    float var = tss / cnt - mean * mean;
    float sc = g[o] * (1.0f / sqrtf(var + EPSV));
    float tt = beta[o] - mean * sc;

    {
        float vv = (sc >= 0.f) ? mx : mn;
        float z = sc * vv + tt;
        val_sh[b][n] = z >= 0.f ? z : 0.2f * z;
    }
    __syncthreads();

    long ro = ((long)b * 2 * Co + o) * NPTS;
    long rt = ((long)b * 2 * Co + Co + o) * NPTS;
    float tp = 0.5f * (val_sh[0][n] + val_sh[1][n]);
    slice[ro + n] = (f16)val_sh[b][n];
    slice[rt + n] = (f16)tp;
}

// ---------------- transpose f16 [b][C][n] -> f16 [b][n][8160] at offc ------
__global__ __launch_bounds__(256) void transpose_cn(
    const f16* __restrict__ slice, f16* __restrict__ xc,
    int Ctot, int offc)
{
    __shared__ u16 t[32][36];
    int c0 = blockIdx.x * 32, n0 = blockIdx.y * 32, b = blockIdx.z;
    const f16* S = slice + (long)b * Ctot * NPTS;
    int tid = threadIdx.x;
    int r = tid >> 3, s4 = (tid & 7) * 4;

    f16x4 v = *(const f16x4*)&S[(long)(c0 + r) * NPTS + n0 + s4];
    t[r][s4 + 0] = ((const u16*)&v)[0];
    t[r][s4 + 1] = ((const u16*)&v)[1];
    t[r][s4 + 2] = ((const u16*)&v)[2];
    t[r][s4 + 3] = ((const u16*)&v)[3];
    __syncthreads();

    long base = ((long)b * NPTS + n0 + r) * 8160 + offc + c0 + s4;
    f16x4 hv;
    u16* hp = (u16*)&hv;
#pragma unroll
    for (int j = 0; j < 4; ++j) hp[j] = t[s4 + j][r];
    *(f16x4*)&xc[base] = hv;
}

// ---------------- final BN + lrelu -> fp32 out (sums 32 partial y planes) ---
__global__ __launch_bounds__(256) void final_bn(const float* __restrict__ y,
                                                const float* __restrict__ g4,
                                                const float* __restrict__ b4,
                                                float* __restrict__ out) {
    __shared__ float red[8];
    int o = blockIdx.x;
    int tid = threadIdx.x;
    int lane = tid & 63, w = tid >> 6;

    float v[4];
    float s = 0.f, ss = 0.f;
#pragma unroll
    for (int b = 0; b < 4; ++b) {
        float acc = 0.f;
#pragma unroll
        for (int sp = 0; sp < 32; ++sp)
            acc += y[sp * 262144 + b * 65536 + o * 256 + tid];
        v[b] = acc;
        s += acc;
        ss += acc * acc;
    }
#pragma unroll
    for (int off = 32; off; off >>= 1) {
        s += __shfl_xor(s, off);
        ss += __shfl_xor(ss, off);
    }
    if (lane == 0) { red[w] = s; red[4 + w] = ss; }
    __syncthreads();
    s = (red[0] + red[1]) + (red[2] + red[3]);
    ss = (red[4] + red[5]) + (red[6] + red[7]);
    float mean = s / 1024.f;
    float var = ss / 1024.f - mean * mean;
    float sc = g4[o] * (1.0f / sqrtf(var + EPSV));
    float tt = b4[o] - mean * sc;
#pragma unroll
    for (int b = 0; b < 4; ++b) {
        float z = sc * v[b] + tt;
        z = z >= 0.f ? z : 0.2f * z;
        out[(long)b * 65536 + o * 256 + tid] = z;
    }
}

// ---------------- launch ----------------
extern "C" void kernel_launch(void* const* d_in, const int* in_sizes, int n_in,
                              void* d_out, int out_size, void* d_ws, size_t ws_size,
                              hipStream_t stream) {
    const float* x = (const float*)d_in[0];
    const float* wl[4];
    const float* gl[4];
    const float* bl[4];
    for (int i = 0; i < 4; ++i) {
        wl[i] = (const float*)d_in[1 + 3 * i];
        gl[i] = (const float*)d_in[2 + 3 * i];
        bl[i] = (const float*)d_in[3 + 3 * i];
    }
    const float* w4 = (const float*)d_in[13];
    const float* g4 = (const float*)d_in[14];
    const float* b4 = (const float*)d_in[15];

    char* ws = (char*)d_ws;
    int* idx = (int*)(ws + OFF_IDX);
    f16* xyz = (f16*)(ws + OFF_XYZ);
    float* PQ = (float*)(ws + OFF_PQ);
    f16* slice = (f16*)(ws + OFF_SLICE);
    f16* xc = (f16*)(ws + OFF_XC);
    float* y = (float*)(ws + OFF_Y);

    // kNN (blocks 0..255, contiguous head) + weight prep (blocks 256..4556)
    knn_prep<<<dim3(4557), dim3(256), 0, stream>>>(x, idx, xyz,
                                                   wl[0], wl[1], wl[2], wl[3], w4, ws);

    const int Kp[4] = {32, 96, 384, 1536};     // padded K (multiples of 32)
    const int Co[4] = {48, 192, 768, 3072};
    const int offc[4] = {0, 96, 480, 2016};
    const int inoff[4] = {0, 0, 96, 480};
    const int nsp[4] = {1, 3, 2, 1};
    const long aoff[4] = {OFF_A0, OFF_A1, OFF_A2, OFF_A3};

    for (int i = 0; i < 4; ++i) {
        int M = 2 * Co[i];
        int Mpad = (M + 127) & ~127;
        const f16* A = (const f16*)(ws + aoff[i]);

        const f16* Bp;
        int ldF;
        long bsF;
        if (i == 0) { Bp = xyz; ldF = 32; bsF = (long)NPTS * 32; }
        else { Bp = xc + inoff[i]; ldF = 8160; bsF = (long)NPTS * 8160; }

        long pstride = (long)NB * M * NPTS;   // one partial plane
        gemm_mfma<<<dim3(Mpad / 128, NPTS / 128, NB * nsp[i]), dim3(256), 0, stream>>>(
            A, Bp, PQ, M, Kp[i], Kp[i], ldF, bsF, (long)M * NPTS, nsp[i], pstride);

        gather_finalize<<<dim3(Co[i]), dim3(1024), 0, stream>>>(
            PQ, pstride, nsp[i], idx, gl[i], bl[i], slice, Co[i]);
        transpose_cn<<<dim3(M / 32, NPTS / 32, NB), dim3(256), 0, stream>>>(
            slice, xc, M, offc[i]);
    }

    // final projection: split-K=32 into 32 private y planes, summed in final_bn
    gemm_mfma<<<dim3(2, NPTS / 128, NB * 32), dim3(256), 0, stream>>>(
        (const f16*)(ws + OFF_A4), xc, y, 256, 8160, 8160, 8160,
        (long)NPTS * 8160, (long)256 * NPTS, 32, (long)NB * 256 * NPTS);
    final_bn<<<dim3(256), dim3(256), 0, stream>>>(y, g4, b4, (float*)d_out);
}

// Round 15
// 255.071 us; speedup vs baseline: 1.3106x; 1.0209x over previous
//
#include <hip/hip_runtime.h>
#include <hip/hip_bf16.h>

#define NPTS 256
#define NB   4
#define KNN  27
#define EPSV 1e-5f

typedef unsigned short u16;
typedef _Float16 f16;
typedef __attribute__((ext_vector_type(8))) _Float16 f16x8;
typedef __attribute__((ext_vector_type(4))) _Float16 f16x4;
typedef __attribute__((ext_vector_type(4))) float f32x4;

// ---------------- workspace layout (bytes); ws = 256 MiB ----------------
#define OFF_IDX    0           // 1024*28*4 = 114688 (idx stride padded to 28)
#define OFF_XYZ    131072      // 4*256*32*2 = 65536   f16 [b][n][32]
#define OFF_A0     262144      // 128*32*2    = 8192
#define OFF_A1     270336      // 384*96*2    = 73728
#define OFF_A2     344064      // 1536*384*2  = 1179648
#define OFF_A3     1523712     // 6144*1536*2 = 18874368
#define OFF_A4     20398080    // 256*8160*2  = 4177920
#define OFF_PQ     24576000    // partial planes
#define OFF_SLICE  74907648    // f16: 4*6144*256*2 = 12582912
#define OFF_XC     100073472   // 4*256*8160*2 = 16711680  f16 [b][n][8160]
#define OFF_Y      116785152   // 16*4*256*256*4 = 16777216
// end ~134 MB

// ---------------- global -> LDS direct DMA (16B/lane) ----------------
typedef __attribute__((address_space(3))) unsigned int lds_u32_t;
typedef __attribute__((address_space(1))) unsigned int glb_u32_t;

__device__ __forceinline__ void gload16(const f16* g, const u16* l) {
    __builtin_amdgcn_global_load_lds((const glb_u32_t*)g, (lds_u32_t*)(u16*)l, 16, 0, 0);
}

__device__ __forceinline__ float dist3_nocontract(float ax, float ay, float az,
                                                  float bx, float by, float bz) {
#pragma clang fp contract(off)
    float dx = bx - ax, dy = by - ay, dz = bz - az;
    float s = dx * dx;
    s = s + dy * dy;
    s = s + dz * dz;
    return s;
}

// ---------------- kNN + weight prep, one dispatch ----------------
// blocks [0,256): kNN, 4 points per block (one per wave), contiguous head
// (r11 lesson: power-of-2 interleaves alias onto few CUs — slot mod 256).
// blocks [256, 4557): weight prep, pbid = bid - 256.
__global__ __launch_bounds__(256) void knn_prep(
    const float* __restrict__ x, int* __restrict__ idx, f16* __restrict__ xyz,
    const float* __restrict__ w0, const float* __restrict__ w1,
    const float* __restrict__ w2, const float* __restrict__ w3,
    const float* __restrict__ w4, char* __restrict__ ws)
{
    int bid = blockIdx.x;
    int tid = threadIdx.x;

    if (bid < 256) {
        int wid = tid >> 6;
        int lane = tid & 63;
        int pt = bid * 4 + wid;         // 0..1023
        int b = pt >> 8, n = pt & 255;

        float xp0 = x[pt * 3 + 0];
        float xp1 = x[pt * 3 + 1];
        float xp2 = x[pt * 3 + 2];

        if (lane < 32) {
            float v = (lane < 3) ? x[pt * 3 + lane] : 0.f;
            xyz[((long)b * NPTS + n) * 32 + lane] = (f16)v;
        }

        unsigned long long key[4];
#pragma unroll
        for (int u = 0; u < 4; ++u) {
            int j = lane + 64 * u;
            int gj = b * NPTS + j;
            float d = dist3_nocontract(xp0, xp1, xp2,
                                       x[gj * 3 + 0], x[gj * 3 + 1], x[gj * 3 + 2]);
            key[u] = ((unsigned long long)__float_as_uint(d) << 32) | (unsigned int)j;
        }

        for (int r = 0; r < KNN; ++r) {
            unsigned long long m = key[0];
            m = key[1] < m ? key[1] : m;
            m = key[2] < m ? key[2] : m;
            m = key[3] < m ? key[3] : m;
#pragma unroll
            for (int off = 32; off; off >>= 1) {
                unsigned long long o = __shfl_xor(m, off);
                m = o < m ? o : m;
            }
            if (lane == 0) idx[pt * 28 + r] = (int)(m & 0xffffffffu);
#pragma unroll
            for (int u = 0; u < 4; ++u)
                if (key[u] == m) key[u] = ~0ULL;
        }
        return;
    }

    int pbid = bid - 256;

    if (pbid == 0) {
        // ---- w0: K=3, Kpad=32, Co=48; rows 0..95 values, 96..127 zero ----
        f16* A = (f16*)(ws + OFF_A0);
        int jj = tid >> 2;              // 0..63
        int cc = (tid & 3) * 8;         // 0,8,16,24
        if (jj < 48) {
            f16x8 lo = {}, df = {};
#pragma unroll
            for (int j = 0; j < 8; ++j) {
                int c = cc + j;
                if (c < 3) {
                    float a = w0[jj * 6 + c];
                    float b2 = w0[jj * 6 + 3 + c];
                    lo[j] = (f16)a;
                    df[j] = (f16)(b2 - a);
                }
            }
            *(f16x8*)&A[jj * 32 + cc] = lo;
            *(f16x8*)&A[(48 + jj) * 32 + cc] = df;
        }
        if (jj < 32) {                  // zero rows 96..127
            f16x8 z = {};
            *(f16x8*)&A[(96 + jj) * 32 + cc] = z;
        }
        return;
    }
    if (pbid < 13) {
        // ---- w1: K=96, Co=192; 16 rows/block, 16 thr/row (12 active) ----
        f16* A = (f16*)(ws + OFF_A1);
        int j = (pbid - 1) * 16 + (tid >> 4);
        int cc = (tid & 15) * 8;
        if (cc >= 96) return;
        f32x4 a0 = *(const f32x4*)&w1[j * 192 + cc];
        f32x4 a1 = *(const f32x4*)&w1[j * 192 + cc + 4];
        f32x4 b0 = *(const f32x4*)&w1[j * 192 + 96 + cc];
        f32x4 b1 = *(const f32x4*)&w1[j * 192 + 96 + cc + 4];
        f16x8 lo, df;
#pragma unroll
        for (int j2 = 0; j2 < 4; ++j2) {
            lo[j2] = (f16)a0[j2];     lo[4 + j2] = (f16)a1[j2];
            df[j2] = (f16)(b0[j2] - a0[j2]);
            df[4 + j2] = (f16)(b1[j2] - a1[j2]);
        }
        *(f16x8*)&A[j * 96 + cc] = lo;
        *(f16x8*)&A[(192 + j) * 96 + cc] = df;
        return;
    }
    if (pbid < 205) {
        // ---- w2: K=384, Co=768; 4 rows/block, 64 thr/row (48 active) ----
        f16* A = (f16*)(ws + OFF_A2);
        int j = (pbid - 13) * 4 + (tid >> 6);
        int cc = (tid & 63) * 8;
        if (cc >= 384) return;
        f32x4 a0 = *(const f32x4*)&w2[(long)j * 768 + cc];
        f32x4 a1 = *(const f32x4*)&w2[(long)j * 768 + cc + 4];
        f32x4 b0 = *(const f32x4*)&w2[(long)j * 768 + 384 + cc];
        f32x4 b1 = *(const f32x4*)&w2[(long)j * 768 + 384 + cc + 4];
        f16x8 lo, df;
#pragma unroll
        for (int j2 = 0; j2 < 4; ++j2) {
            lo[j2] = (f16)a0[j2];     lo[4 + j2] = (f16)a1[j2];
            df[j2] = (f16)(b0[j2] - a0[j2]);
            df[4 + j2] = (f16)(b1[j2] - a1[j2]);
        }
        *(f16x8*)&A[(long)j * 384 + cc] = lo;
        *(f16x8*)&A[(long)(768 + j) * 384 + cc] = df;
        return;
    }
    if (pbid < 3277) {
        // ---- w3: K=1536, Co=3072; 1 row/block, 192 thr active ----
        f16* A = (f16*)(ws + OFF_A3);
        int j = pbid - 205;
        int cc = tid * 8;
        if (cc >= 1536) return;
        f32x4 a0 = *(const f32x4*)&w3[(long)j * 3072 + cc];
        f32x4 a1 = *(const f32x4*)&w3[(long)j * 3072 + cc + 4];
        f32x4 b0 = *(const f32x4*)&w3[(long)j * 3072 + 1536 + cc];
        f32x4 b1 = *(const f32x4*)&w3[(long)j * 3072 + 1536 + cc + 4];
        f16x8 lo, df;
#pragma unroll
        for (int j2 = 0; j2 < 4; ++j2) {
            lo[j2] = (f16)a0[j2];     lo[4 + j2] = (f16)a1[j2];
            df[j2] = (f16)(b0[j2] - a0[j2]);
            df[4 + j2] = (f16)(b1[j2] - a1[j2]);
        }
        *(f16x8*)&A[(long)j * 1536 + cc] = lo;
        *(f16x8*)&A[(long)(3072 + j) * 1536 + cc] = df;
        return;
    }
    {
        // ---- w4: 256 x 8160, straight copy to f16 ----
        f16* A = (f16*)(ws + OFF_A4);
        int loc = pbid - 3277;
        int r = loc >> 2;
        int c0 = (loc & 3) * 2048 + tid * 8;
        if (c0 >= 8160) return;
        f32x4 a0 = *(const f32x4*)&w4[(long)r * 8160 + c0];
        f32x4 a1 = *(const f32x4*)&w4[(long)r * 8160 + c0 + 4];
        f16x8 hv;
#pragma unroll
        for (int j2 = 0; j2 < 4; ++j2) {
            hv[j2] = (f16)a0[j2];
            hv[4 + j2] = (f16)a1[j2];
        }
        *(f16x8*)&A[(long)r * 8160 + c0] = hv;
        return;
    }
}

// ---------------- f16 MFMA GEMM, split-K, depth-4 counted-vmcnt pipeline ----
// [FROZEN — r7 config, measured optimum across 5 variants (r2/r6/r7/r8/r9).
//  BN=64 regresses (LDS-read ratio); BK=64 depth-2 regresses (loses counted
//  depth). 256^2-tile templates structurally unfit: N=256/batch caps grid.]
__global__ __launch_bounds__(256) void gemm_mfma(
    const f16* __restrict__ A, const f16* __restrict__ B,
    float* __restrict__ out, int M, int Kpad, int K,
    int ldF, long bsF, long bsO, int nsplit, long pstride)
{
    __shared__ u16 sS[4][2][4096];     // [buf][A/B][128*32]

    int bz = blockIdx.z;
    int b = bz / nsplit, slice = bz - b * nsplit;
    int kchunk = (((K + nsplit - 1) / nsplit) + 31) & ~31;
    int kstart = slice * kchunk;
    int kend = K < kstart + kchunk ? K : kstart + kchunk;
    int nt = (kend - kstart) >> 5;          // K multiple of 32 always

    const f16* pB = B + (long)b * bsF;
    float* Ob = out + (long)slice * pstride + (long)b * bsO;

    int m0 = blockIdx.x * 128, n0 = blockIdx.y * 128;
    int tid = threadIdx.x, lane = tid & 63, wid = tid >> 6;
    int wm = (wid >> 1) * 64, wn = (wid & 1) * 64;
    int lrow = lane & 15, quad = lane >> 4;

    int r0 = wid * 16 + (lane >> 2);
    int r1 = 64 + r0;
    int ck = lane & 3;
    int c0 = (ck ^ ((r0 >> 1) & 3)) * 8;
    int c1 = (ck ^ ((r1 >> 1) & 3)) * 8;

    const f16* gA0 = A + (long)(m0 + r0) * Kpad + c0 + kstart;
    const f16* gA1 = A + (long)(m0 + r1) * Kpad + c1 + kstart;
    const f16* gB0 = pB + (long)(n0 + r0) * ldF + c0 + kstart;
    const f16* gB1 = pB + (long)(n0 + r1) * ldF + c1 + kstart;

    int oA0 = (wid * 16) * 32;              // wave-uniform LDS element offsets
    int oA1 = (64 + wid * 16) * 32;

    int fs = (quad ^ ((lrow >> 1) & 3)) * 8;
    int offA = (wm + lrow) * 32 + fs;
    int offB = (wn + lrow) * 32 + fs;

    f32x4 acc[4][4] = {};

#define STAGE(bf)                                                  \
    do {                                                           \
        gload16(gA0, &sS[bf][0][oA0]);                             \
        gload16(gA1, &sS[bf][0][oA1]);                             \
        gload16(gB0, &sS[bf][1][oA0]);                             \
        gload16(gB1, &sS[bf][1][oA1]);                             \
        gA0 += 32; gA1 += 32; gB0 += 32; gB1 += 32;                \
    } while (0)

    // prologue: stage up to 3 tiles (oldest first)
    STAGE(0);
    if (nt > 1) STAGE(1);
    if (nt > 2) STAGE(2);

    for (int t = 0; t < nt; ++t) {
        int rem = nt - 1 - t;
        if (rem >= 2)      asm volatile("s_waitcnt vmcnt(8)" ::: "memory");
        else if (rem == 1) asm volatile("s_waitcnt vmcnt(4)" ::: "memory");
        else               asm volatile("s_waitcnt vmcnt(0)" ::: "memory");
        __builtin_amdgcn_s_barrier();

        if (t + 3 < nt) STAGE((t + 3) & 3);

        const u16* bA = &sS[t & 3][0][0];
        const u16* bB = &sS[t & 3][1][0];
        f16x8 fb[4];
#pragma unroll
        for (int nt4 = 0; nt4 < 4; ++nt4)
            fb[nt4] = *(const f16x8*)&bB[offB + nt4 * 512];
        __builtin_amdgcn_s_setprio(1);
#pragma unroll
        for (int mt = 0; mt < 4; ++mt) {
            f16x8 fa = *(const f16x8*)&bA[offA + mt * 512];
#pragma unroll
            for (int nt4 = 0; nt4 < 4; ++nt4)
                acc[mt][nt4] = __builtin_amdgcn_mfma_f32_16x16x32_f16(fa, fb[nt4], acc[mt][nt4], 0, 0, 0);
        }
        __builtin_amdgcn_s_setprio(0);
    }
#undef STAGE

    // epilogue: C/D layout col=lane&15, row=quad*4+reg  [m89-verified]
#pragma unroll
    for (int mt = 0; mt < 4; ++mt)
#pragma unroll
        for (int nt4 = 0; nt4 < 4; ++nt4) {
            int C = n0 + wn + nt4 * 16 + lrow;
            int Rb = m0 + wm + mt * 16 + quad * 4;
#pragma unroll
            for (int r = 0; r < 4; ++r) {
                int R = Rb + r;
                if (R < M) Ob[(long)R * NPTS + C] = acc[mt][nt4][r];
            }
        }
}

// ---------------- fused gather + stats + BN/lrelu + tp concat ---------------
// 512 threads: b = tid>>7, each thread handles 2 n-values. 2-deep pipelined
// int4 idx consumption. [r13: fused transposed write = scatter-stores, keep
// split transpose_cn. r14: 1024-thr neutral, final split-K 32 costs its own
// traffic — both reverted.]
__global__ __launch_bounds__(512) void gather_finalize(
    const float* __restrict__ PQ, long pstride, int nsplit,
    const int* __restrict__ idx,
    const float* __restrict__ g, const float* __restrict__ beta,
    f16* __restrict__ slice, int Co)
{
    __shared__ float p_sh[NB][NPTS];
    __shared__ float val_sh[NB][NPTS];
    __shared__ float red[2][NB][2];
    int o = blockIdx.x;
    int tid = threadIdx.x;
    int b = tid >> 7;           // 0..3
    int l128 = tid & 127;       // 0..127
    int wh = (tid >> 6) & 1;    // wave-half within b-group

    long ip0 = ((long)b * 2 * Co + o) * NPTS;
    long iq0 = ((long)b * 2 * Co + Co + o) * NPTS;

    float qv[2];
#pragma unroll
    for (int u = 0; u < 2; ++u) {
        int n = l128 + 128 * u;
        float v = 0.f, q = 0.f;
        for (int sp2 = 0; sp2 < nsplit; ++sp2) {
            v += PQ[sp2 * pstride + ip0 + n];
            q += PQ[sp2 * pstride + iq0 + n];
        }
        p_sh[b][n] = v;
        qv[u] = q;
    }
    __syncthreads();

#define G3(cu)                                                      \
    { float p;                                                      \
      p = p_sh[b][cu.x]; sp += p; spp = fmaf(p, p, spp);            \
      pmx = fmaxf(pmx, p); pmn = fminf(pmn, p);                     \
      p = p_sh[b][cu.y]; sp += p; spp = fmaf(p, p, spp);            \
      pmx = fmaxf(pmx, p); pmn = fminf(pmn, p);                     \
      p = p_sh[b][cu.z]; sp += p; spp = fmaf(p, p, spp);            \
      pmx = fmaxf(pmx, p); pmn = fminf(pmn, p); }
#define G4(cu)                                                      \
    { G3(cu);                                                       \
      float p = p_sh[b][cu.w]; sp += p; spp = fmaf(p, p, spp);      \
      pmx = fmaxf(pmx, p); pmn = fminf(pmn, p); }

    float mx[2], mn[2];
    float s = 0.f, ss = 0.f;
#pragma unroll
    for (int u = 0; u < 2; ++u) {
        int n = l128 + 128 * u;
        const int4* ip4 = (const int4*)(idx + ((long)b * NPTS + n) * 28);

        float sp = 0.f, spp = 0.f;
        float pmx = -__builtin_inff(), pmn = __builtin_inff();

        int4 t0 = ip4[0];
        int4 t1 = ip4[1];
        G4(t0); t0 = ip4[2];        // k 0..3
        G4(t1); t1 = ip4[3];        // k 4..7
        G4(t0); t0 = ip4[4];        // k 8..11
        G4(t1); t1 = ip4[5];        // k 12..15
        G4(t0); t0 = ip4[6];        // k 16..19
        G4(t1);                     // k 20..23
        G3(t0);                     // k 24..26 (slot 27 = pad, unused)

        float q = qv[u];
        s += sp + 27.f * q;
        ss += spp + q * fmaf(2.f, sp, 27.f * q);
        mx[u] = pmx + q;
        mn[u] = pmn + q;
    }
#undef G4
#undef G3

#pragma unroll
    for (int off = 32; off; off >>= 1) {
        s += __shfl_xor(s, off);
        ss += __shfl_xor(ss, off);
    }
    if ((tid & 63) == 0) { red[0][b][wh] = s; red[1][b][wh] = ss; }
    __syncthreads();

    float ts = ((red[0][0][0] + red[0][0][1]) + (red[0][1][0] + red[0][1][1]))
             + ((red[0][2][0] + red[0][2][1]) + (red[0][3][0] + red[0][3][1]));
    float tss = ((red[1][0][0] + red[1][0][1]) + (red[1][1][0] + red[1][1][1]))
              + ((red[1][2][0] + red[1][2][1]) + (red[1][3][0] + red[1][3][1]));
    const float cnt = (float)(NB * NPTS * KNN);
    float mean = ts / cnt;
    float var = tss / cnt - mean * mean;
    float sc = g[o] * (1.0f / sqrtf(var + EPSV));
    float tt = beta[o] - mean * sc;

#pragma unroll
    for (int u = 0; u < 2; ++u) {
        int n = l128 + 128 * u;
        float v = (sc >= 0.f) ? mx[u] : mn[u];
        float z = sc * v + tt;
        val_sh[b][n] = z >= 0.f ? z : 0.2f * z;
    }
    __syncthreads();

    long ro = ((long)b * 2 * Co + o) * NPTS;
    long rt = ((long)b * 2 * Co + Co + o) * NPTS;
#pragma unroll
    for (int u = 0; u < 2; ++u) {
        int n = l128 + 128 * u;
        float tp = 0.5f * (val_sh[0][n] + val_sh[1][n]);
        slice[ro + n] = (f16)val_sh[b][n];
        slice[rt + n] = (f16)tp;
    }
}

// ---------------- transpose f16 [b][C][n] -> f16 [b][n][8160] at offc ------
__global__ __launch_bounds__(256) void transpose_cn(
    const f16* __restrict__ slice, f16* __restrict__ xc,
    int Ctot, int offc)
{
    __shared__ u16 t[32][36];
    int c0 = blockIdx.x * 32, n0 = blockIdx.y * 32, b = blockIdx.z;
    const f16* S = slice + (long)b * Ctot * NPTS;
    int tid = threadIdx.x;
    int r = tid >> 3, s4 = (tid & 7) * 4;

    f16x4 v = *(const f16x4*)&S[(long)(c0 + r) * NPTS + n0 + s4];
    t[r][s4 + 0] = ((const u16*)&v)[0];
    t[r][s4 + 1] = ((const u16*)&v)[1];
    t[r][s4 + 2] = ((const u16*)&v)[2];
    t[r][s4 + 3] = ((const u16*)&v)[3];
    __syncthreads();

    long base = ((long)b * NPTS + n0 + r) * 8160 + offc + c0 + s4;
    f16x4 hv;
    u16* hp = (u16*)&hv;
#pragma unroll
    for (int j = 0; j < 4; ++j) hp[j] = t[s4 + j][r];
    *(f16x4*)&xc[base] = hv;
}

// ---------------- final BN + lrelu -> fp32 out (sums 16 partial y planes) ---
__global__ __launch_bounds__(256) void final_bn(const float* __restrict__ y,
                                                const float* __restrict__ g4,
                                                const float* __restrict__ b4,
                                                float* __restrict__ out) {
    __shared__ float red[8];
    int o = blockIdx.x;
    int tid = threadIdx.x;
    int lane = tid & 63, w = tid >> 6;

    float v[4];
    float s = 0.f, ss = 0.f;
#pragma unroll
    for (int b = 0; b < 4; ++b) {
        float acc = 0.f;
#pragma unroll
        for (int sp = 0; sp < 16; ++sp)
            acc += y[sp * 262144 + b * 65536 + o * 256 + tid];
        v[b] = acc;
        s += acc;
        ss += acc * acc;
    }
#pragma unroll
    for (int off = 32; off; off >>= 1) {
        s += __shfl_xor(s, off);
        ss += __shfl_xor(ss, off);
    }
    if (lane == 0) { red[w] = s; red[4 + w] = ss; }
    __syncthreads();
    s = (red[0] + red[1]) + (red[2] + red[3]);
    ss = (red[4] + red[5]) + (red[6] + red[7]);
    float mean = s / 1024.f;
    float var = ss / 1024.f - mean * mean;
    float sc = g4[o] * (1.0f / sqrtf(var + EPSV));
    float tt = b4[o] - mean * sc;
#pragma unroll
    for (int b = 0; b < 4; ++b) {
        float z = sc * v[b] + tt;
        z = z >= 0.f ? z : 0.2f * z;
        out[(long)b * 65536 + o * 256 + tid] = z;
    }
}

// ---------------- launch ----------------
extern "C" void kernel_launch(void* const* d_in, const int* in_sizes, int n_in,
                              void* d_out, int out_size, void* d_ws, size_t ws_size,
                              hipStream_t stream) {
    const float* x = (const float*)d_in[0];
    const float* wl[4];
    const float* gl[4];
    const float* bl[4];
    for (int i = 0; i < 4; ++i) {
        wl[i] = (const float*)d_in[1 + 3 * i];
        gl[i] = (const float*)d_in[2 + 3 * i];
        bl[i] = (const float*)d_in[3 + 3 * i];
    }
    const float* w4 = (const float*)d_in[13];
    const float* g4 = (const float*)d_in[14];
    const float* b4 = (const float*)d_in[15];

    char* ws = (char*)d_ws;
    int* idx = (int*)(ws + OFF_IDX);
    f16* xyz = (f16*)(ws + OFF_XYZ);
    float* PQ = (float*)(ws + OFF_PQ);
    f16* slice = (f16*)(ws + OFF_SLICE);
    f16* xc = (f16*)(ws + OFF_XC);
    float* y = (float*)(ws + OFF_Y);

    // kNN (blocks 0..255, contiguous head) + weight prep (blocks 256..4556)
    knn_prep<<<dim3(4557), dim3(256), 0, stream>>>(x, idx, xyz,
                                                   wl[0], wl[1], wl[2], wl[3], w4, ws);

    const int Kp[4] = {32, 96, 384, 1536};     // padded K (multiples of 32)
    const int Co[4] = {48, 192, 768, 3072};
    const int offc[4] = {0, 96, 480, 2016};
    const int inoff[4] = {0, 0, 96, 480};
    const int nsp[4] = {1, 3, 2, 1};
    const long aoff[4] = {OFF_A0, OFF_A1, OFF_A2, OFF_A3};

    for (int i = 0; i < 4; ++i) {
        int M = 2 * Co[i];
        int Mpad = (M + 127) & ~127;
        const f16* A = (const f16*)(ws + aoff[i]);

        const f16* Bp;
        int ldF;
        long bsF;
        if (i == 0) { Bp = xyz; ldF = 32; bsF = (long)NPTS * 32; }
        else { Bp = xc + inoff[i]; ldF = 8160; bsF = (long)NPTS * 8160; }

        long pstride = (long)NB * M * NPTS;   // one partial plane
        gemm_mfma<<<dim3(Mpad / 128, NPTS / 128, NB * nsp[i]), dim3(256), 0, stream>>>(
            A, Bp, PQ, M, Kp[i], Kp[i], ldF, bsF, (long)M * NPTS, nsp[i], pstride);

        gather_finalize<<<dim3(Co[i]), dim3(512), 0, stream>>>(
            PQ, pstride, nsp[i], idx, gl[i], bl[i], slice, Co[i]);
        transpose_cn<<<dim3(M / 32, NPTS / 32, NB), dim3(256), 0, stream>>>(
            slice, xc, M, offc[i]);
    }

    // final projection: split-K=16 into 16 private y planes, summed in final_bn
    gemm_mfma<<<dim3(2, NPTS / 128, NB * 16), dim3(256), 0, stream>>>(
        (const f16*)(ws + OFF_A4), xc, y, 256, 8160, 8160, 8160,
        (long)NPTS * 8160, (long)256 * NPTS, 16, (long)NB * 256 * NPTS);
    final_bn<<<dim3(256), dim3(256), 0, stream>>>(y, g4, b4, (float*)d_out);
}